// Round 7
// baseline (192.888 us; speedup 1.0000x reference)
//
#include <hip/hip_runtime.h>
#include <stdint.h>
#include <stddef.h>
#include <algorithm>

// Problem constants (fixed by the reference file)
#define BATCH  1024
#define S1     25
#define S2     10
#define DIM    256
#define NNEIB  64
#define L2ROWS (BATCH * S1)          // 25600
#define MROWS  (BATCH + BATCH * S1)  // 26624 (multiple of 128)
#define KTOT   512                   // GEMM K = [X | M]
#define NFEAT  50000

struct Perm25 { int p[S1]; };
struct Perm10 { int p[S2]; };

typedef __attribute__((ext_vector_type(8))) short short8;
typedef __attribute__((ext_vector_type(4))) float f32x4;

// ======================= host-side JAX threefry replication ==================
static inline uint32_t rotl_(uint32_t x, int d) { return (x << d) | (x >> (32 - d)); }

static void tf2x32(uint32_t k0, uint32_t k1, uint32_t x0, uint32_t x1,
                   uint32_t* o0, uint32_t* o1) {
  const uint32_t ks0 = k0, ks1 = k1, ks2 = k0 ^ k1 ^ 0x1BD11BDAu;
  static const int R[8] = {13, 15, 26, 6, 17, 29, 16, 24};
  x0 += ks0; x1 += ks1;
  for (int g = 0; g < 5; ++g) {
    const int* rr = R + (g & 1) * 4;
    for (int i = 0; i < 4; i++) { x0 += x1; x1 = rotl_(x1, rr[i]); x1 ^= x0; }
    uint32_t a, b;
    switch (g) {
      default:
      case 0: a = ks1; b = ks2; break;
      case 1: a = ks2; b = ks0; break;
      case 2: a = ks0; b = ks1; break;
      case 3: a = ks1; b = ks2; break;
      case 4: a = ks2; b = ks0; break;
    }
    x0 += a; x1 = x1 + b + (uint32_t)(g + 1);
  }
  *o0 = x0; *o1 = x1;
}

// jax.random.permutation(fold_in(key(42), li), 64), partitionable threefry
// (verified correct R1-R6).
static void compute_perm(uint32_t li, int n, int* out) {
  uint32_t k0, k1, s0, s1;
  tf2x32(0u, 42u, 0u, li, &k0, &k1);
  tf2x32(k0, k1, 0u, 1u, &s0, &s1);
  uint32_t bits[NNEIB];
  for (int i = 0; i < NNEIB; i++) {
    uint32_t a, b;
    tf2x32(s0, s1, 0u, (uint32_t)i, &a, &b);
    bits[i] = a ^ b;
  }
  int idx[NNEIB];
  for (int i = 0; i < NNEIB; i++) idx[i] = i;
  std::stable_sort(idx, idx + NNEIB, [&](int A, int B) { return bits[A] < bits[B]; });
  for (int j = 0; j < n; j++) out[j] = idx[j];
}

// ============================ device helpers =================================
__device__ __forceinline__ unsigned short f2bf(float x) {
  union { float f; uint32_t u; } v; v.f = x;
  uint32_t r = (v.u + 0x7FFFu + ((v.u >> 16) & 1u)) >> 16;   // RNE
  return (unsigned short)r;
}
__device__ __forceinline__ float bfbits2f(uint32_t lo16) {
  union { uint32_t u; float f; } v; v.u = lo16 << 16;
  return v.f;
}

// ================================ kernels ====================================

// Fused prep: [0,12500) convf | [12500,13012) convw W1 | [13012,13524) convw W2
// | [13524,13528) sample1. All partitions independent.
#define PREP_CONVF   12500   // NFEAT*DIM/4/256
#define PREP_CONVW   512     // DIM*KTOT/256
#define PREP_BLOCKS  (PREP_CONVF + 2 * PREP_CONVW + 4)
__global__ __launch_bounds__(256) void prep_k(
    const float* __restrict__ feats, uint32_t* __restrict__ fb,
    const float* __restrict__ Wx1, const float* __restrict__ Wn1,
    unsigned short* __restrict__ Wt1,
    const float* __restrict__ Wx2, const float* __restrict__ Wn2,
    unsigned short* __restrict__ Wt2,
    const int* __restrict__ ids, const int* __restrict__ dix,
    const float* __restrict__ dval, int* __restrict__ idx1,
    float* __restrict__ w1, Perm25 pm) {
  int b = blockIdx.x, t = threadIdx.x;
  if (b < PREP_CONVF) {
    int i = b * 256 + t;
    f32x4 v = *(const f32x4*)&feats[(size_t)i * 4];
    fb[(size_t)i * 2]     = f2bf(v.x) | ((uint32_t)f2bf(v.y) << 16);
    fb[(size_t)i * 2 + 1] = f2bf(v.z) | ((uint32_t)f2bf(v.w) << 16);
  } else if (b < PREP_CONVF + 2 * PREP_CONVW) {
    int wi = b - PREP_CONVF;
    const float* Wx = (wi < PREP_CONVW) ? Wx1 : Wx2;
    const float* Wn = (wi < PREP_CONVW) ? Wn1 : Wn2;
    unsigned short* Wt = (wi < PREP_CONVW) ? Wt1 : Wt2;
    int idx = (wi % PREP_CONVW) * 256 + t;
    int n = idx >> 9, k = idx & 511;
    float v = (k < DIM) ? Wx[(size_t)k * DIM + n] : Wn[(size_t)(k - DIM) * DIM + n];
    Wt[(size_t)n * KTOT + k] = f2bf(v);
  } else {
    int i = (b - PREP_CONVF - 2 * PREP_CONVW) * 256 + t;
    if (i >= BATCH) return;
    int nid = ids[i];
    const float* vr = dval + (size_t)nid * NNEIB;
    const int* ir = dix + (size_t)nid * NNEIB;
    float v[S1];
    float s = 0.f;
    for (int j = 0; j < S1; j++) { v[j] = vr[pm.p[j]]; s += v[j]; }
    float inv = 1.f / (s + 1e-10f);
    for (int j = 0; j < S1; j++) {
      w1[i * S1 + j] = v[j] * inv;
      idx1[i * S1 + j] = ir[pm.p[j]];
    }
  }
}

// stage1 (with inline layer-1 sampling): M1[r] = wmean of bf16 neighbor rows.
// Wave-per-row, 4 rows/block.
__global__ __launch_bounds__(256) void stage1_k(
    const uint2* __restrict__ fb, const int* __restrict__ idx1,
    const float* __restrict__ w1, const int* __restrict__ dix,
    const float* __restrict__ dval, Perm10 pm2, uint2* __restrict__ M1) {
  int wave = threadIdx.x >> 6, lane = threadIdx.x & 63;
  int r = blockIdx.x * 4 + wave;
  int s, nbl = 0;
  float wl = 0.f;
  if (r < BATCH) {
    s = S1;
    if (lane < S1) { nbl = idx1[r * S1 + lane]; wl = w1[r * S1 + lane]; }
  } else {
    s = S2;
    int nx = idx1[r - BATCH];
    float vj = 0.f;
    if (lane < S2) {
      int c = pm2.p[lane];
      nbl = dix[(size_t)nx * NNEIB + c];
      vj = dval[(size_t)nx * NNEIB + c];
    }
    float tot = 0.f;
    for (int j = 0; j < S2; j++) tot += __shfl(vj, j);
    wl = vj / (tot + 1e-10f);
  }
  float a0 = 0.f, a1 = 0.f, a2 = 0.f, a3 = 0.f;
  for (int j = 0; j < s; j++) {
    int nid = __shfl(nbl, j);
    float wj = __shfl(wl, j);
    uint2 u = fb[(size_t)nid * 64 + lane];
    a0 += wj * bfbits2f(u.x & 0xffffu);
    a1 += wj * bfbits2f(u.x >> 16);
    a2 += wj * bfbits2f(u.y & 0xffffu);
    a3 += wj * bfbits2f(u.y >> 16);
  }
  uint2 o;
  o.x = f2bf(a0) | ((uint32_t)f2bf(a1) << 16);
  o.y = f2bf(a2) | ((uint32_t)f2bf(a3) << 16);
  M1[(size_t)r * 64 + lane] = o;
}

// stage2: M2[i] = wmean over H rows 1024+i*25+j with w1. Wave-per-row.
__global__ __launch_bounds__(256) void stage2_k(
    const uint2* __restrict__ Hb, const float* __restrict__ w1,
    uint2* __restrict__ M2) {
  int wave = threadIdx.x >> 6, lane = threadIdx.x & 63;
  int i = blockIdx.x * 4 + wave;
  float wl = (lane < S1) ? w1[(size_t)i * S1 + lane] : 0.f;
  const uint2* hb = Hb + (size_t)(BATCH + i * S1) * 64 + lane;
  float a0 = 0.f, a1 = 0.f, a2 = 0.f, a3 = 0.f;
  for (int j = 0; j < S1; j++) {
    float wj = __shfl(wl, j);
    uint2 u = hb[(size_t)j * 64];
    a0 += wj * bfbits2f(u.x & 0xffffu);
    a1 += wj * bfbits2f(u.x >> 16);
    a2 += wj * bfbits2f(u.y & 0xffffu);
    a3 += wj * bfbits2f(u.y >> 16);
  }
  uint2 o;
  o.x = f2bf(a0) | ((uint32_t)f2bf(a1) << 16);
  o.y = f2bf(a2) | ((uint32_t)f2bf(a3) << 16);
  M2[(size_t)i * 64 + lane] = o;
}

// bf16 MFMA GEMM with virtual A = [X | M]. BK=32, R4 grid order (x=row).
// WavesM x WavesN wave grid. Layer 1 uses TBN=256 (single column pass: A
// read once, 208-block balanced grid); layer 2 uses 64x64.
// Fragment layouts HW-verified (m89/m91).
#define BK 32
#define LPAD 40   // LDS row stride (bf16): 80 B -> 2-way bank aliasing (free)
template <int TBM, int TBN, int WM, int WN, bool OUT_BF16>
__global__ __launch_bounds__(256) void gemm_k(
    const unsigned short* __restrict__ Xsrc, const int* __restrict__ ids,
    const int* __restrict__ idx1, const unsigned short* __restrict__ Mh,
    const unsigned short* __restrict__ Wt, const float* __restrict__ bx,
    const float* __restrict__ bn, void* __restrict__ OutP) {
  constexpr int MI = TBM / (WM * 16);   // a-frags per wave
  constexpr int NJ = TBN / (WN * 16);   // b-frags per wave
  __shared__ __align__(16) unsigned short As[TBM][LPAD];
  __shared__ __align__(16) unsigned short Bs[TBN][LPAD];
  int t = threadIdx.x;
  int wave = t >> 6, lane = t & 63, quad = lane >> 4, l16 = lane & 15;
  int wm = (wave / WN) * (TBM / WM);
  int wn = (wave % WN) * (TBN / WN);
  int row0 = blockIdx.x * TBM, col0 = blockIdx.y * TBN;

  f32x4 acc[MI][NJ];
#pragma unroll
  for (int i = 0; i < MI; i++)
#pragma unroll
    for (int j = 0; j < NJ; j++) acc[i][j] = (f32x4){0.f, 0.f, 0.f, 0.f};

  int lr = t >> 2;            // 0..63
  int lq = (t & 3) * 8;       // k chunk offset
  int xrow[TBM / 64];
#pragma unroll
  for (int p = 0; p < TBM / 64; p++) {
    int gr = row0 + p * 64 + lr;
    xrow[p] = ids ? ((gr < BATCH) ? ids[gr] : idx1[gr - BATCH]) : gr;
  }

  for (int k0 = 0; k0 < KTOT; k0 += BK) {
#pragma unroll
    for (int p = 0; p < TBM / 64; p++) {
      const unsigned short* src =
          (k0 < DIM) ? (Xsrc + (size_t)xrow[p] * DIM + k0 + lq)
                     : (Mh + (size_t)(row0 + p * 64 + lr) * DIM + (k0 - DIM) + lq);
      *(f32x4*)&As[p * 64 + lr][lq] = *(const f32x4*)src;
    }
#pragma unroll
    for (int p = 0; p < TBN / 64; p++)
      *(f32x4*)&Bs[p * 64 + lr][lq] =
          *(const f32x4*)&Wt[(size_t)(col0 + p * 64 + lr) * KTOT + k0 + lq];
    __syncthreads();

    short8 af[MI], bfr[NJ];
#pragma unroll
    for (int i = 0; i < MI; i++)
      af[i] = *(const short8*)&As[wm + i * 16 + l16][quad * 8];
#pragma unroll
    for (int j = 0; j < NJ; j++)
      bfr[j] = *(const short8*)&Bs[wn + j * 16 + l16][quad * 8];
#pragma unroll
    for (int i = 0; i < MI; i++)
#pragma unroll
      for (int j = 0; j < NJ; j++)
        acc[i][j] = __builtin_amdgcn_mfma_f32_16x16x32_bf16(af[i], bfr[j], acc[i][j], 0, 0, 0);
    __syncthreads();
  }

  // Epilogue: bias + relu. D layout: col = l16, row = quad*4 + reg.
  float bias[NJ];
#pragma unroll
  for (int j = 0; j < NJ; j++) {
    int c = col0 + wn + j * 16 + l16;
    bias[j] = bx[c] + bn[c];
  }
#pragma unroll
  for (int i = 0; i < MI; i++) {
#pragma unroll
    for (int j = 0; j < NJ; j++) {
      int c = col0 + wn + j * 16 + l16;
#pragma unroll
      for (int reg = 0; reg < 4; reg++) {
        int r = row0 + wm + i * 16 + quad * 4 + reg;
        float v = fmaxf(acc[i][j][reg] + bias[j], 0.f);
        if (OUT_BF16)
          ((unsigned short*)OutP)[(size_t)r * DIM + c] = f2bf(v);
        else
          ((float*)OutP)[(size_t)r * DIM + c] = v;
      }
    }
  }
}

// ================================ launcher ===================================
static inline size_t align256(size_t x) { return (x + 255) & ~(size_t)255; }

extern "C" void kernel_launch(void* const* d_in, const int* in_sizes, int n_in,
                              void* d_out, int out_size, void* d_ws, size_t ws_size,
                              hipStream_t stream) {
  const int*   ids  = (const int*)d_in[0];
  const int*   dix  = (const int*)d_in[1];
  const float* dval = (const float*)d_in[2];
  const float* feats= (const float*)d_in[3];
  const float* Wx1  = (const float*)d_in[4];
  const float* bx1  = (const float*)d_in[5];
  const float* Wn1  = (const float*)d_in[6];
  const float* bn1  = (const float*)d_in[7];
  const float* Wx2  = (const float*)d_in[8];
  const float* bx2  = (const float*)d_in[9];
  const float* Wn2  = (const float*)d_in[10];
  const float* bn2  = (const float*)d_in[11];
  float* out = (float*)d_out;

  Perm25 p25;
  Perm10 p10;
  compute_perm(0u, S1, p25.p);
  compute_perm(1u, S2, p10.p);

  // Workspace carve-up (~54 MB).
  char* w = (char*)d_ws;
  int*            idx1 = (int*)w;            w += align256(sizeof(int) * L2ROWS);
  float*          w1   = (float*)w;          w += align256(sizeof(float) * L2ROWS);
  uint32_t*       fb   = (uint32_t*)w;       w += align256(2 * (size_t)NFEAT * DIM);
  unsigned short* M1   = (unsigned short*)w; w += align256(2 * (size_t)MROWS * DIM);
  unsigned short* Hb   = (unsigned short*)w; w += align256(2 * (size_t)MROWS * DIM);
  unsigned short* M2   = (unsigned short*)w; w += align256(2 * (size_t)BATCH * DIM);
  unsigned short* Wt1  = (unsigned short*)w; w += align256(2 * (size_t)DIM * KTOT);
  unsigned short* Wt2  = (unsigned short*)w; w += align256(2 * (size_t)DIM * KTOT);

  prep_k<<<PREP_BLOCKS, 256, 0, stream>>>(feats, fb, Wx1, Wn1, Wt1, Wx2, Wn2, Wt2,
                                          ids, dix, dval, idx1, w1, p25);
  stage1_k<<<MROWS / 4, 256, 0, stream>>>((const uint2*)fb, idx1, w1, dix, dval, p10,
                                          (uint2*)M1);
  // Layer-1 GEMM: TBN=256 single column pass; wave grid 2x2 (wave tile 64x128).
  gemm_k<128, 256, 2, 2, true><<<dim3(MROWS / 128, 1), 256, 0, stream>>>(
      (const unsigned short*)fb, ids, idx1, M1, Wt1, bx1, bn1, Hb);
  stage2_k<<<BATCH / 4, 256, 0, stream>>>((const uint2*)Hb, w1, (uint2*)M2);
  gemm_k<64, 64, 2, 2, false><<<dim3(BATCH / 64, DIM / 64), 256, 0, stream>>>(
      Hb, nullptr, nullptr, M2, Wt2, bx2, bn2, out);
}

// Round 8
// 188.376 us; speedup vs baseline: 1.0240x; 1.0240x over previous
//
#include <hip/hip_runtime.h>
#include <stdint.h>
#include <stddef.h>
#include <algorithm>

// Problem constants (fixed by the reference file)
#define BATCH  1024
#define S1     25
#define S2     10
#define DIM    256
#define NNEIB  64
#define L2ROWS (BATCH * S1)          // 25600
#define MROWS  (BATCH + BATCH * S1)  // 26624 (multiple of 128)
#define KTOT   512                   // GEMM K = [X | M]
#define NFEAT  50000

struct Perm25 { int p[S1]; };
struct Perm10 { int p[S2]; };

typedef __attribute__((ext_vector_type(8))) short short8;
typedef __attribute__((ext_vector_type(4))) float f32x4;

// ======================= host-side JAX threefry replication ==================
static inline uint32_t rotl_(uint32_t x, int d) { return (x << d) | (x >> (32 - d)); }

static void tf2x32(uint32_t k0, uint32_t k1, uint32_t x0, uint32_t x1,
                   uint32_t* o0, uint32_t* o1) {
  const uint32_t ks0 = k0, ks1 = k1, ks2 = k0 ^ k1 ^ 0x1BD11BDAu;
  static const int R[8] = {13, 15, 26, 6, 17, 29, 16, 24};
  x0 += ks0; x1 += ks1;
  for (int g = 0; g < 5; ++g) {
    const int* rr = R + (g & 1) * 4;
    for (int i = 0; i < 4; i++) { x0 += x1; x1 = rotl_(x1, rr[i]); x1 ^= x0; }
    uint32_t a, b;
    switch (g) {
      default:
      case 0: a = ks1; b = ks2; break;
      case 1: a = ks2; b = ks0; break;
      case 2: a = ks0; b = ks1; break;
      case 3: a = ks1; b = ks2; break;
      case 4: a = ks2; b = ks0; break;
    }
    x0 += a; x1 = x1 + b + (uint32_t)(g + 1);
  }
  *o0 = x0; *o1 = x1;
}

// jax.random.permutation(fold_in(key(42), li), 64), partitionable threefry
// (verified correct R1-R7).
static void compute_perm(uint32_t li, int n, int* out) {
  uint32_t k0, k1, s0, s1;
  tf2x32(0u, 42u, 0u, li, &k0, &k1);
  tf2x32(k0, k1, 0u, 1u, &s0, &s1);
  uint32_t bits[NNEIB];
  for (int i = 0; i < NNEIB; i++) {
    uint32_t a, b;
    tf2x32(s0, s1, 0u, (uint32_t)i, &a, &b);
    bits[i] = a ^ b;
  }
  int idx[NNEIB];
  for (int i = 0; i < NNEIB; i++) idx[i] = i;
  std::stable_sort(idx, idx + NNEIB, [&](int A, int B) { return bits[A] < bits[B]; });
  for (int j = 0; j < n; j++) out[j] = idx[j];
}

// ============================ device helpers =================================
__device__ __forceinline__ unsigned short f2bf(float x) {
  union { float f; uint32_t u; } v; v.f = x;
  uint32_t r = (v.u + 0x7FFFu + ((v.u >> 16) & 1u)) >> 16;   // RNE
  return (unsigned short)r;
}
__device__ __forceinline__ float bfbits2f(uint32_t lo16) {
  union { uint32_t u; float f; } v; v.u = lo16 << 16;
  return v.f;
}

// ================================ kernels ====================================

// Fused prep: [0,12500) convf | [12500,13012) convw W1 | [13012,13524) convw W2
// | [13524,13528) sample1. All partitions independent.
#define PREP_CONVF   12500   // NFEAT*DIM/4/256
#define PREP_CONVW   512     // DIM*KTOT/256
#define PREP_BLOCKS  (PREP_CONVF + 2 * PREP_CONVW + 4)
__global__ __launch_bounds__(256) void prep_k(
    const float* __restrict__ feats, uint32_t* __restrict__ fb,
    const float* __restrict__ Wx1, const float* __restrict__ Wn1,
    unsigned short* __restrict__ Wt1,
    const float* __restrict__ Wx2, const float* __restrict__ Wn2,
    unsigned short* __restrict__ Wt2,
    const int* __restrict__ ids, const int* __restrict__ dix,
    const float* __restrict__ dval, int* __restrict__ idx1,
    float* __restrict__ w1, Perm25 pm) {
  int b = blockIdx.x, t = threadIdx.x;
  if (b < PREP_CONVF) {
    int i = b * 256 + t;
    f32x4 v = *(const f32x4*)&feats[(size_t)i * 4];
    fb[(size_t)i * 2]     = f2bf(v.x) | ((uint32_t)f2bf(v.y) << 16);
    fb[(size_t)i * 2 + 1] = f2bf(v.z) | ((uint32_t)f2bf(v.w) << 16);
  } else if (b < PREP_CONVF + 2 * PREP_CONVW) {
    int wi = b - PREP_CONVF;
    const float* Wx = (wi < PREP_CONVW) ? Wx1 : Wx2;
    const float* Wn = (wi < PREP_CONVW) ? Wn1 : Wn2;
    unsigned short* Wt = (wi < PREP_CONVW) ? Wt1 : Wt2;
    int idx = (wi % PREP_CONVW) * 256 + t;
    int n = idx >> 9, k = idx & 511;
    float v = (k < DIM) ? Wx[(size_t)k * DIM + n] : Wn[(size_t)(k - DIM) * DIM + n];
    Wt[(size_t)n * KTOT + k] = f2bf(v);
  } else {
    int i = (b - PREP_CONVF - 2 * PREP_CONVW) * 256 + t;
    if (i >= BATCH) return;
    int nid = ids[i];
    const float* vr = dval + (size_t)nid * NNEIB;
    const int* ir = dix + (size_t)nid * NNEIB;
    float v[S1];
    float s = 0.f;
    for (int j = 0; j < S1; j++) { v[j] = vr[pm.p[j]]; s += v[j]; }
    float inv = 1.f / (s + 1e-10f);
    for (int j = 0; j < S1; j++) {
      w1[i * S1 + j] = v[j] * inv;
      idx1[i * S1 + j] = ir[pm.p[j]];
    }
  }
}

// stage1 (with inline layer-1 sampling): M1[r] = wmean of bf16 neighbor rows.
// Wave-per-row, 4 rows/block.
__global__ __launch_bounds__(256) void stage1_k(
    const uint2* __restrict__ fb, const int* __restrict__ idx1,
    const float* __restrict__ w1, const int* __restrict__ dix,
    const float* __restrict__ dval, Perm10 pm2, uint2* __restrict__ M1) {
  int wave = threadIdx.x >> 6, lane = threadIdx.x & 63;
  int r = blockIdx.x * 4 + wave;
  int s, nbl = 0;
  float wl = 0.f;
  if (r < BATCH) {
    s = S1;
    if (lane < S1) { nbl = idx1[r * S1 + lane]; wl = w1[r * S1 + lane]; }
  } else {
    s = S2;
    int nx = idx1[r - BATCH];
    float vj = 0.f;
    if (lane < S2) {
      int c = pm2.p[lane];
      nbl = dix[(size_t)nx * NNEIB + c];
      vj = dval[(size_t)nx * NNEIB + c];
    }
    float tot = 0.f;
    for (int j = 0; j < S2; j++) tot += __shfl(vj, j);
    wl = vj / (tot + 1e-10f);
  }
  float a0 = 0.f, a1 = 0.f, a2 = 0.f, a3 = 0.f;
  for (int j = 0; j < s; j++) {
    int nid = __shfl(nbl, j);
    float wj = __shfl(wl, j);
    uint2 u = fb[(size_t)nid * 64 + lane];
    a0 += wj * bfbits2f(u.x & 0xffffu);
    a1 += wj * bfbits2f(u.x >> 16);
    a2 += wj * bfbits2f(u.y & 0xffffu);
    a3 += wj * bfbits2f(u.y >> 16);
  }
  uint2 o;
  o.x = f2bf(a0) | ((uint32_t)f2bf(a1) << 16);
  o.y = f2bf(a2) | ((uint32_t)f2bf(a3) << 16);
  M1[(size_t)r * 64 + lane] = o;
}

// stage2: M2[i] = wmean over H rows 1024+i*25+j with w1. Wave-per-row.
__global__ __launch_bounds__(256) void stage2_k(
    const uint2* __restrict__ Hb, const float* __restrict__ w1,
    uint2* __restrict__ M2) {
  int wave = threadIdx.x >> 6, lane = threadIdx.x & 63;
  int i = blockIdx.x * 4 + wave;
  float wl = (lane < S1) ? w1[(size_t)i * S1 + lane] : 0.f;
  const uint2* hb = Hb + (size_t)(BATCH + i * S1) * 64 + lane;
  float a0 = 0.f, a1 = 0.f, a2 = 0.f, a3 = 0.f;
  for (int j = 0; j < S1; j++) {
    float wj = __shfl(wl, j);
    uint2 u = hb[(size_t)j * 64];
    a0 += wj * bfbits2f(u.x & 0xffffu);
    a1 += wj * bfbits2f(u.x >> 16);
    a2 += wj * bfbits2f(u.y & 0xffffu);
    a3 += wj * bfbits2f(u.y >> 16);
  }
  uint2 o;
  o.x = f2bf(a0) | ((uint32_t)f2bf(a1) << 16);
  o.y = f2bf(a2) | ((uint32_t)f2bf(a3) << 16);
  M2[(size_t)i * 64 + lane] = o;
}

// bf16 MFMA GEMM with virtual A = [X | M] (R4 best-measured config: BK=32,
// blockIdx.x = row block, 2x2 wave grid). Fragment layouts HW-verified
// (m89/m91): A[m=lane&15][k=quad*8+j], B=Wt[n][k] same shape,
// D col=lane&15 row=quad*4+reg.
#define BK 32
#define LPAD 40   // LDS row stride (bf16): 80 B -> 2-way bank aliasing (free)
template <int TBM, int TBN, bool OUT_BF16>
__global__ __launch_bounds__(256) void gemm_k(
    const unsigned short* __restrict__ Xsrc, const int* __restrict__ ids,
    const int* __restrict__ idx1, const unsigned short* __restrict__ Mh,
    const unsigned short* __restrict__ Wt, const float* __restrict__ bx,
    const float* __restrict__ bn, void* __restrict__ OutP) {
  constexpr int MI = TBM / 32;
  constexpr int NJ = TBN / 32;
  __shared__ __align__(16) unsigned short As[TBM][LPAD];
  __shared__ __align__(16) unsigned short Bs[TBN][LPAD];
  int t = threadIdx.x;
  int wave = t >> 6, lane = t & 63, quad = lane >> 4, l16 = lane & 15;
  int wm = (wave >> 1) * (TBM / 2);
  int wn = (wave & 1) * (TBN / 2);
  int row0 = blockIdx.x * TBM, col0 = blockIdx.y * TBN;

  f32x4 acc[MI][NJ];
#pragma unroll
  for (int i = 0; i < MI; i++)
#pragma unroll
    for (int j = 0; j < NJ; j++) acc[i][j] = (f32x4){0.f, 0.f, 0.f, 0.f};

  int lr = t >> 2;
  int lq = (t & 3) * 8;
  int xrow[TBM / 64];
#pragma unroll
  for (int p = 0; p < TBM / 64; p++) {
    int gr = row0 + p * 64 + lr;
    xrow[p] = ids ? ((gr < BATCH) ? ids[gr] : idx1[gr - BATCH]) : gr;
  }

  for (int k0 = 0; k0 < KTOT; k0 += BK) {
#pragma unroll
    for (int p = 0; p < TBM / 64; p++) {
      const unsigned short* src =
          (k0 < DIM) ? (Xsrc + (size_t)xrow[p] * DIM + k0 + lq)
                     : (Mh + (size_t)(row0 + p * 64 + lr) * DIM + (k0 - DIM) + lq);
      *(f32x4*)&As[p * 64 + lr][lq] = *(const f32x4*)src;
    }
#pragma unroll
    for (int p = 0; p < TBN / 64; p++)
      *(f32x4*)&Bs[p * 64 + lr][lq] =
          *(const f32x4*)&Wt[(size_t)(col0 + p * 64 + lr) * KTOT + k0 + lq];
    __syncthreads();

    short8 af[MI], bfr[NJ];
#pragma unroll
    for (int i = 0; i < MI; i++)
      af[i] = *(const short8*)&As[wm + i * 16 + l16][quad * 8];
#pragma unroll
    for (int j = 0; j < NJ; j++)
      bfr[j] = *(const short8*)&Bs[wn + j * 16 + l16][quad * 8];
#pragma unroll
    for (int i = 0; i < MI; i++)
#pragma unroll
      for (int j = 0; j < NJ; j++)
        acc[i][j] = __builtin_amdgcn_mfma_f32_16x16x32_bf16(af[i], bfr[j], acc[i][j], 0, 0, 0);
    __syncthreads();
  }

  // Epilogue: bias + relu. D layout: col = l16, row = quad*4 + reg.
  float bias[NJ];
#pragma unroll
  for (int j = 0; j < NJ; j++) {
    int c = col0 + wn + j * 16 + l16;
    bias[j] = bx[c] + bn[c];
  }
#pragma unroll
  for (int i = 0; i < MI; i++) {
#pragma unroll
    for (int j = 0; j < NJ; j++) {
      int c = col0 + wn + j * 16 + l16;
#pragma unroll
      for (int reg = 0; reg < 4; reg++) {
        int r = row0 + wm + i * 16 + quad * 4 + reg;
        float v = fmaxf(acc[i][j][reg] + bias[j], 0.f);
        if (OUT_BF16)
          ((unsigned short*)OutP)[(size_t)r * DIM + c] = f2bf(v);
        else
          ((float*)OutP)[(size_t)r * DIM + c] = v;
      }
    }
  }
}

// ================================ launcher ===================================
static inline size_t align256(size_t x) { return (x + 255) & ~(size_t)255; }

extern "C" void kernel_launch(void* const* d_in, const int* in_sizes, int n_in,
                              void* d_out, int out_size, void* d_ws, size_t ws_size,
                              hipStream_t stream) {
  const int*   ids  = (const int*)d_in[0];
  const int*   dix  = (const int*)d_in[1];
  const float* dval = (const float*)d_in[2];
  const float* feats= (const float*)d_in[3];
  const float* Wx1  = (const float*)d_in[4];
  const float* bx1  = (const float*)d_in[5];
  const float* Wn1  = (const float*)d_in[6];
  const float* bn1  = (const float*)d_in[7];
  const float* Wx2  = (const float*)d_in[8];
  const float* bx2  = (const float*)d_in[9];
  const float* Wn2  = (const float*)d_in[10];
  const float* bn2  = (const float*)d_in[11];
  float* out = (float*)d_out;

  Perm25 p25;
  Perm10 p10;
  compute_perm(0u, S1, p25.p);
  compute_perm(1u, S2, p10.p);

  // Workspace carve-up (~54 MB).
  char* w = (char*)d_ws;
  int*            idx1 = (int*)w;            w += align256(sizeof(int) * L2ROWS);
  float*          w1   = (float*)w;          w += align256(sizeof(float) * L2ROWS);
  uint32_t*       fb   = (uint32_t*)w;       w += align256(2 * (size_t)NFEAT * DIM);
  unsigned short* M1   = (unsigned short*)w; w += align256(2 * (size_t)MROWS * DIM);
  unsigned short* Hb   = (unsigned short*)w; w += align256(2 * (size_t)MROWS * DIM);
  unsigned short* M2   = (unsigned short*)w; w += align256(2 * (size_t)BATCH * DIM);
  unsigned short* Wt1  = (unsigned short*)w; w += align256(2 * (size_t)DIM * KTOT);
  unsigned short* Wt2  = (unsigned short*)w; w += align256(2 * (size_t)DIM * KTOT);

  prep_k<<<PREP_BLOCKS, 256, 0, stream>>>(feats, fb, Wx1, Wn1, Wt1, Wx2, Wn2, Wt2,
                                          ids, dix, dval, idx1, w1, p25);
  stage1_k<<<MROWS / 4, 256, 0, stream>>>((const uint2*)fb, idx1, w1, dix, dval, p10,
                                          (uint2*)M1);
  gemm_k<128, 128, true><<<dim3(MROWS / 128, DIM / 128), 256, 0, stream>>>(
      (const unsigned short*)fb, ids, idx1, M1, Wt1, bx1, bn1, Hb);
  stage2_k<<<BATCH / 4, 256, 0, stream>>>((const uint2*)Hb, w1, (uint2*)M2);
  gemm_k<64, 64, false><<<dim3(BATCH / 64, DIM / 64), 256, 0, stream>>>(
      Hb, nullptr, nullptr, M2, Wt2, bx2, bn2, out);
}